// Round 11
// baseline (568.875 us; speedup 1.0000x reference)
//
#include <hip/hip_runtime.h>
#include <hip/hip_bf16.h>

#define NN 50000
#define NE 800000
#define DD 64
#define NEG 0.2f

#define RFL(x) __builtin_amdgcn_readfirstlane(x)

// ---------------- CSR build ----------------
__global__ void k_hist(const int* __restrict__ dst1, const int* __restrict__ dst2,
                       int* __restrict__ cnt1, int* __restrict__ cnt2) {
    int e = blockIdx.x * blockDim.x + threadIdx.x;
    if (e < NE) {
        atomicAdd(&cnt1[dst1[e]], 1);
        atomicAdd(&cnt2[dst2[e]], 1);
    }
}

__global__ __launch_bounds__(1024) void k_scan(const int* __restrict__ cnt1, int* __restrict__ off1,
                                               const int* __restrict__ cnt2, int* __restrict__ off2) {
    const int* cnt = blockIdx.x ? cnt2 : cnt1;
    int* off = blockIdx.x ? off2 : off1;
    __shared__ int lds[1024];
    const int tid = threadIdx.x;
    const int CH = (NN + 1023) / 1024;  // 49
    const int base = tid * CH;
    int s = 0;
    for (int q = 0; q < CH; ++q) {
        int idx = base + q;
        if (idx < NN) s += cnt[idx];
    }
    lds[tid] = s;
    __syncthreads();
    for (int d = 1; d < 1024; d <<= 1) {
        int v = (tid >= d) ? lds[tid - d] : 0;
        __syncthreads();
        lds[tid] += v;
        __syncthreads();
    }
    int run = tid ? lds[tid - 1] : 0;
    for (int q = 0; q < CH; ++q) {
        int idx = base + q;
        if (idx < NN) { off[idx] = run; run += cnt[idx]; }
    }
    if (tid == 1023) off[NN] = lds[1023];
}

__global__ void k_scatter(const int* __restrict__ src1, const int* __restrict__ dst1,
                          const int* __restrict__ off1, int* __restrict__ fill1, int* __restrict__ csr1,
                          const int* __restrict__ src2, const int* __restrict__ dst2,
                          const int* __restrict__ off2, int* __restrict__ fill2, int* __restrict__ csr2) {
    int e = blockIdx.x * blockDim.x + threadIdx.x;
    if (e < NE) {
        int d1 = dst1[e];
        int p1 = off1[d1] + atomicAdd(&fill1[d1], 1);
        csr1[p1] = src1[e];
        int d2 = dst2[e];
        int p2 = off2[d2] + atomicAdd(&fill2[d2], 1);
        csr2[p2] = src2[e];
    }
}

// ---------------- H1 = x @ W1, alpha1 = H1 @ a1_{src,dst} ----------------
__global__ __launch_bounds__(256) void k_h1(
    const float* __restrict__ x, const float* __restrict__ W1,
    const float* __restrict__ a1s, const float* __restrict__ a1d,
    float* __restrict__ H1, float* __restrict__ al1s, float* __restrict__ al1d) {
    const int lane = threadIdx.x & 63;
    const int i = blockIdx.x * 4 + (threadIdx.x >> 6);
    const float xv = x[i * DD + lane];
    float h = 0.f;
#pragma unroll
    for (int j = 0; j < DD; ++j) h = fmaf(__shfl(xv, j), W1[j * DD + lane], h);
    H1[i * DD + lane] = h;
    float ps = h * a1s[lane], pd = h * a1d[lane];
#pragma unroll
    for (int o = 32; o; o >>= 1) { ps += __shfl_xor(ps, o); pd += __shfl_xor(pd, o); }
    if (lane == 0) { al1s[i] = ps; al1d[i] = pd; }
}

// ---------------- t2s = W2 @ a2s, t2d = W2 @ a2d ----------------
__global__ void k_a2t(const float* __restrict__ W2, const float* __restrict__ a2s,
                      const float* __restrict__ a2d, float* __restrict__ t2s,
                      float* __restrict__ t2d) {
    int j = threadIdx.x & 63;
    float ss = 0.f, sd = 0.f;
#pragma unroll
    for (int d = 0; d < DD; ++d) {
        float w = W2[j * DD + d];
        ss = fmaf(w, a2s[d], ss);
        sd = fmaf(w, a2d[d], sd);
    }
    t2s[j] = ss;
    t2d[j] = sd;
}

// ---- layer1: phase A (parallel score+den) -> LDS -> phase B (lean gather) ----
__global__ __launch_bounds__(256) void k_l1(
    const int* __restrict__ off, const int* __restrict__ csrc,
    const float* __restrict__ al1s, const float* __restrict__ al1d,
    const float* __restrict__ H1,
    const float* __restrict__ t2s, const float* __restrict__ t2d,
    uint4* __restrict__ H2a, _Float16* __restrict__ H2b,
    float* __restrict__ al2s8, float* __restrict__ al2s9, float* __restrict__ al2d) {
    __shared__ int2 lsr[4][64];
    const int lane = threadIdx.x & 63;
    const int wid = threadIdx.x >> 6;
    const int i = blockIdx.x * 4 + wid;
    const int p0 = RFL(off[i]);
    const int p1 = RFL(off[i + 1]);
    const float adv = al1d[i];
    float num[9], den[9];
#pragma unroll
    for (int k = 0; k < 9; ++k) { num[k] = 0.f; den[k] = 0.f; }

    for (int base = p0; base < p1; base += 64) {
        int m = p1 - base; if (m > 64) m = 64;
        // phase A: one edge per lane
        int sv = 0; float rv = 0.f;
        if (lane < m) {
            sv = csrc[base + lane];
            float z = al1s[sv] + adv;
            float c = z > 0.f ? z : NEG * z;       // leaky_relu (step-invariant)
            rv = __expf(c * (1.f / 9.f));          // w_k = rv^k
        }
        {
            float w = rv;
#pragma unroll
            for (int k = 0; k < 9; ++k) { den[k] += w; w *= rv; }  // per-lane partials
        }
        lsr[wid][lane] = make_int2(sv, __float_as_int(rv));
        asm volatile("s_waitcnt lgkmcnt(0)" ::: "memory");
        // phase B: serial, LDS broadcast (s,r), one gather + 18 VALU per edge
        int j = 0;
        for (; j + 1 < m; j += 2) {
            int2 e0 = lsr[wid][j];
            int2 e1 = lsr[wid][j + 1];
            float h0 = H1[(size_t)e0.x * DD + lane];
            float h1v = H1[(size_t)e1.x * DD + lane];
            float r0 = __int_as_float(e0.y), r1 = __int_as_float(e1.y);
            float w0 = r0, w1 = r1;
#pragma unroll
            for (int k = 0; k < 9; ++k) {
                num[k] = fmaf(w0, h0, num[k]);  w0 *= r0;
                num[k] = fmaf(w1, h1v, num[k]); w1 *= r1;
            }
        }
        if (j < m) {
            int2 e0 = lsr[wid][j];
            float h0 = H1[(size_t)e0.x * DD + lane];
            float r0 = __int_as_float(e0.y);
            float w0 = r0;
#pragma unroll
            for (int k = 0; k < 9; ++k) { num[k] = fmaf(w0, h0, num[k]); w0 *= r0; }
        }
    }
    // reduce den partials across lanes
#pragma unroll
    for (int k = 0; k < 9; ++k) {
#pragma unroll
        for (int o = 32; o; o >>= 1) den[k] += __shfl_xor(den[k], o);
    }

    const float tss = t2s[lane];
    const float tdd = t2d[lane];
    float hm[9];
#pragma unroll
    for (int k = 0; k < 9; ++k) {
        float t = (float)(k + 1) * (1.f / 9.f);
        float v = (den[k] > 0.f) ? (t * num[k] / den[k]) : 0.f;
        hm[k] = (v > 0.f) ? v : expm1f(v);         // ELU
    }
#pragma unroll
    for (int k = 0; k < 9; ++k) {
        float ps = hm[k] * tss, pd = hm[k] * tdd;
#pragma unroll
        for (int o = 32; o; o >>= 1) { ps += __shfl_xor(ps, o); pd += __shfl_xor(pd, o); }
        if (lane == 0) {
            if (k < 8) al2s8[(size_t)i * 8 + k] = ps;
            else       al2s9[i] = ps;
            al2d[(size_t)i * 9 + k] = pd;
        }
    }
    union { _Float16 h[8]; uint4 u; } pk;
#pragma unroll
    for (int k = 0; k < 8; ++k) pk.h[k] = (_Float16)hm[k];
    H2a[(size_t)i * DD + lane] = pk.u;
    H2b[(size_t)i * DD + lane] = (_Float16)hm[8];
}

// ---- layer2: phase A (parallel 9 exps+den) -> LDS -> phase B -> one W2 matvec ----
__global__ __launch_bounds__(256) void k_l2(
    const int* __restrict__ off, const int* __restrict__ csrc,
    const float* __restrict__ al2s8, const float* __restrict__ al2s9,
    const float* __restrict__ al2d,
    const uint4* __restrict__ H2a, const _Float16* __restrict__ H2b,
    const float* __restrict__ W2, float* __restrict__ out) {
    __shared__ float lw[4][64][12];   // [0..8]=w_k, [9]=src bits
    const int lane = threadIdx.x & 63;
    const int wid = threadIdx.x >> 6;
    const int i = blockIdx.x * 4 + wid;
    const int p0 = RFL(off[i]);
    const int p1 = RFL(off[i + 1]);
    float adv[9];
#pragma unroll
    for (int k = 0; k < 9; ++k) adv[k] = al2d[(size_t)i * 9 + k];
    float num[9], den[9];
#pragma unroll
    for (int k = 0; k < 9; ++k) { num[k] = 0.f; den[k] = 0.f; }

    for (int base = p0; base < p1; base += 64) {
        int m = p1 - base; if (m > 64) m = 64;
        // phase A: one edge per lane — parallel alpha gathers + 9 exps
        int sv = 0; float wv[9];
#pragma unroll
        for (int k = 0; k < 9; ++k) wv[k] = 0.f;
        if (lane < m) {
            sv = csrc[base + lane];
            const float4* pa = (const float4*)(al2s8 + (size_t)sv * 8);
            float4 A0 = pa[0], A1 = pa[1];
            float as[9] = {A0.x, A0.y, A0.z, A0.w, A1.x, A1.y, A1.z, A1.w, al2s9[sv]};
#pragma unroll
            for (int k = 0; k < 9; ++k) {
                float z = as[k] + adv[k];
                float lr = z > 0.f ? z : NEG * z;
                wv[k] = __expf(lr);
            }
        }
#pragma unroll
        for (int k = 0; k < 9; ++k) den[k] += wv[k];   // per-lane partials
        float* dst = &lw[wid][lane][0];
        *(float4*)dst       = make_float4(wv[0], wv[1], wv[2], wv[3]);
        *(float4*)(dst + 4) = make_float4(wv[4], wv[5], wv[6], wv[7]);
        dst[8] = wv[8];
        dst[9] = __int_as_float(sv);
        asm volatile("s_waitcnt lgkmcnt(0)" ::: "memory");
        // phase B: serial, 3 broadcast ds_reads + 2 gathers + 9 FMA per edge
#pragma unroll 2
        for (int j = 0; j < m; ++j) {
            const float* src = &lw[wid][j][0];
            float4 wA = *(const float4*)src;
            float4 wB = *(const float4*)(src + 4);
            float w8 = src[8];
            int sj = __float_as_int(src[9]);
            union { uint4 v; _Float16 h[8]; } c;
            c.v = H2a[(size_t)sj * DD + lane];
            float h9 = (float)H2b[(size_t)sj * DD + lane];
            num[0] = fmaf(wA.x, (float)c.h[0], num[0]);
            num[1] = fmaf(wA.y, (float)c.h[1], num[1]);
            num[2] = fmaf(wA.z, (float)c.h[2], num[2]);
            num[3] = fmaf(wA.w, (float)c.h[3], num[3]);
            num[4] = fmaf(wB.x, (float)c.h[4], num[4]);
            num[5] = fmaf(wB.y, (float)c.h[5], num[5]);
            num[6] = fmaf(wB.z, (float)c.h[6], num[6]);
            num[7] = fmaf(wB.w, (float)c.h[7], num[7]);
            num[8] = fmaf(w8, h9, num[8]);
        }
    }
    // reduce den partials across lanes
#pragma unroll
    for (int k = 0; k < 9; ++k) {
#pragma unroll
        for (int o = 32; o; o >>= 1) den[k] += __shfl_xor(den[k], o);
    }
    // vsum[lane] = sum_k num/den, then one W2 matvec per node
    float vsum = 0.f;
#pragma unroll
    for (int k = 0; k < 9; ++k) vsum += (den[k] > 0.f) ? (num[k] / den[k]) : 0.f;
    float h2 = 0.f;
#pragma unroll 8
    for (int j = 0; j < DD; ++j) h2 = fmaf(__shfl(vsum, j), W2[j * DD + lane], h2);
    out[(size_t)i * DD + lane] = h2 * (1.f / 9.f);
}

extern "C" void kernel_launch(void* const* d_in, const int* in_sizes, int n_in,
                              void* d_out, int out_size, void* d_ws, size_t ws_size,
                              hipStream_t stream) {
    const float* x   = (const float*)d_in[0];
    const int*   ei1 = (const int*)d_in[1];
    const int*   ei2 = (const int*)d_in[2];
    const float* W1  = (const float*)d_in[3];
    const float* a1s = (const float*)d_in[4];
    const float* a1d = (const float*)d_in[5];
    const float* W2  = (const float*)d_in[6];
    const float* a2s = (const float*)d_in[7];
    const float* a2d = (const float*)d_in[8];
    float* out = (float*)d_out;

    const int* src1 = ei1;
    const int* dst1 = ei1 + NE;
    const int* src2 = ei2;
    const int* dst2 = ei2 + NE;

    // ---- workspace layout (4-byte words), ~81.6 MB total ----
    uint4* H2a   = (uint4*)d_ws;                          // NN*64 uint4 (51.2 MB)
    float* H1    = (float*)d_ws + (size_t)NN * 256;       // NN*DD
    float* al1s  = H1 + (size_t)NN * DD;                  // NN
    float* al1d  = al1s + NN;                             // NN
    float* al2s8 = al1d + NN;                             // NN*8
    float* al2s9 = al2s8 + (size_t)NN * 8;                // NN
    float* al2d  = al2s9 + NN;                            // NN*9
    _Float16* H2b = (_Float16*)(al2d + (size_t)NN * 9);   // NN*DD halves
    int* off1 = (int*)((float*)H2b + (size_t)NN * DD / 2);// NN+1
    int* off2 = off1 + (NN + 1);                          // NN+1
    int* cnt1 = off2 + (NN + 1);                          // NN
    int* cnt2 = cnt1 + NN;                                // NN (contiguous with cnt1)
    int* csr1 = cnt2 + NN;                                // NE
    int* csr2 = csr1 + NE;                                // NE
    float* t2s = (float*)(csr2 + NE);                     // 64
    float* t2d = t2s + DD;                                // 64

    const int EB = 256, EG = (NE + EB - 1) / EB;
    const int NB = NN / 4;  // wave per node

    hipMemsetAsync(cnt1, 0, 2 * NN * sizeof(int), stream);
    k_hist<<<EG, EB, 0, stream>>>(dst1, dst2, cnt1, cnt2);
    k_scan<<<2, 1024, 0, stream>>>(cnt1, off1, cnt2, off2);
    hipMemsetAsync(cnt1, 0, 2 * NN * sizeof(int), stream);
    k_scatter<<<EG, EB, 0, stream>>>(src1, dst1, off1, cnt1, csr1,
                                     src2, dst2, off2, cnt2, csr2);
    k_h1<<<NB, 256, 0, stream>>>(x, W1, a1s, a1d, H1, al1s, al1d);
    k_a2t<<<1, 64, 0, stream>>>(W2, a2s, a2d, t2s, t2d);

    k_l1<<<NB, 256, 0, stream>>>(off1, csr1, al1s, al1d, H1,
                                 t2s, t2d, H2a, H2b, al2s8, al2s9, al2d);
    k_l2<<<NB, 256, 0, stream>>>(off2, csr2, al2s8, al2s9, al2d, H2a, H2b, W2, out);
}

// Round 12
// 558.526 us; speedup vs baseline: 1.0185x; 1.0185x over previous
//
#include <hip/hip_runtime.h>
#include <hip/hip_bf16.h>

#define NN 50000
#define NE 800000
#define DD 64
#define NEG 0.2f

#define RFL(x) __builtin_amdgcn_readfirstlane(x)

// ---------------- CSR build (4 edges per thread for atomic MLP) ----------------
__global__ void k_hist(const int* __restrict__ dst1, const int* __restrict__ dst2,
                       int* __restrict__ cnt1, int* __restrict__ cnt2) {
    int t = blockIdx.x * blockDim.x + threadIdx.x;
    if (t < NE / 4) {
        int4 d1 = ((const int4*)dst1)[t];
        int4 d2 = ((const int4*)dst2)[t];
        atomicAdd(&cnt1[d1.x], 1); atomicAdd(&cnt1[d1.y], 1);
        atomicAdd(&cnt1[d1.z], 1); atomicAdd(&cnt1[d1.w], 1);
        atomicAdd(&cnt2[d2.x], 1); atomicAdd(&cnt2[d2.y], 1);
        atomicAdd(&cnt2[d2.z], 1); atomicAdd(&cnt2[d2.w], 1);
    }
}

__global__ __launch_bounds__(1024) void k_scan(const int* __restrict__ cnt1, int* __restrict__ off1,
                                               const int* __restrict__ cnt2, int* __restrict__ off2) {
    const int* cnt = blockIdx.x ? cnt2 : cnt1;
    int* off = blockIdx.x ? off2 : off1;
    __shared__ int lds[1024];
    const int tid = threadIdx.x;
    const int CH = (NN + 1023) / 1024;  // 49
    const int base = tid * CH;
    int s = 0;
    for (int q = 0; q < CH; ++q) {
        int idx = base + q;
        if (idx < NN) s += cnt[idx];
    }
    lds[tid] = s;
    __syncthreads();
    for (int d = 1; d < 1024; d <<= 1) {
        int v = (tid >= d) ? lds[tid - d] : 0;
        __syncthreads();
        lds[tid] += v;
        __syncthreads();
    }
    int run = tid ? lds[tid - 1] : 0;
    for (int q = 0; q < CH; ++q) {
        int idx = base + q;
        if (idx < NN) { off[idx] = run; run += cnt[idx]; }
    }
    if (tid == 1023) off[NN] = lds[1023];
}

__global__ void k_scatter(const int* __restrict__ src1, const int* __restrict__ dst1,
                          const int* __restrict__ off1, int* __restrict__ fill1, int* __restrict__ csr1,
                          const int* __restrict__ src2, const int* __restrict__ dst2,
                          const int* __restrict__ off2, int* __restrict__ fill2, int* __restrict__ csr2) {
    int t = blockIdx.x * blockDim.x + threadIdx.x;
    if (t < NE / 4) {
        int4 s1 = ((const int4*)src1)[t];
        int4 d1 = ((const int4*)dst1)[t];
        int4 s2 = ((const int4*)src2)[t];
        int4 d2 = ((const int4*)dst2)[t];
        int pA = off1[d1.x] + atomicAdd(&fill1[d1.x], 1);
        int pB = off1[d1.y] + atomicAdd(&fill1[d1.y], 1);
        int pC = off1[d1.z] + atomicAdd(&fill1[d1.z], 1);
        int pD = off1[d1.w] + atomicAdd(&fill1[d1.w], 1);
        int qA = off2[d2.x] + atomicAdd(&fill2[d2.x], 1);
        int qB = off2[d2.y] + atomicAdd(&fill2[d2.y], 1);
        int qC = off2[d2.z] + atomicAdd(&fill2[d2.z], 1);
        int qD = off2[d2.w] + atomicAdd(&fill2[d2.w], 1);
        csr1[pA] = s1.x; csr1[pB] = s1.y; csr1[pC] = s1.z; csr1[pD] = s1.w;
        csr2[qA] = s2.x; csr2[qB] = s2.y; csr2[qC] = s2.z; csr2[qD] = s2.w;
    }
}

// ---------------- H1 = x @ W1, alpha1 = H1 @ a1_{src,dst} ----------------
__global__ __launch_bounds__(256) void k_h1(
    const float* __restrict__ x, const float* __restrict__ W1,
    const float* __restrict__ a1s, const float* __restrict__ a1d,
    float* __restrict__ H1, float* __restrict__ al1s, float* __restrict__ al1d) {
    const int lane = threadIdx.x & 63;
    const int i = blockIdx.x * 4 + (threadIdx.x >> 6);
    const float xv = x[i * DD + lane];
    float h = 0.f;
#pragma unroll
    for (int j = 0; j < DD; ++j) h = fmaf(__shfl(xv, j), W1[j * DD + lane], h);
    H1[i * DD + lane] = h;
    float ps = h * a1s[lane], pd = h * a1d[lane];
#pragma unroll
    for (int o = 32; o; o >>= 1) { ps += __shfl_xor(ps, o); pd += __shfl_xor(pd, o); }
    if (lane == 0) { al1s[i] = ps; al1d[i] = pd; }
}

// ---------------- t2s = W2 @ a2s, t2d = W2 @ a2d ----------------
__global__ void k_a2t(const float* __restrict__ W2, const float* __restrict__ a2s,
                      const float* __restrict__ a2d, float* __restrict__ t2s,
                      float* __restrict__ t2d) {
    int j = threadIdx.x & 63;
    float ss = 0.f, sd = 0.f;
#pragma unroll
    for (int d = 0; d < DD; ++d) {
        float w = W2[j * DD + d];
        ss = fmaf(w, a2s[d], ss);
        sd = fmaf(w, a2d[d], sd);
    }
    t2s[j] = ss;
    t2d[j] = sd;
}

// ---- layer1: phase A (parallel score+den) -> LDS -> phase B (4 gathers in flight) ----
__global__ __launch_bounds__(256) void k_l1(
    const int* __restrict__ off, const int* __restrict__ csrc,
    const float* __restrict__ al1s, const float* __restrict__ al1d,
    const float* __restrict__ H1,
    const float* __restrict__ t2s, const float* __restrict__ t2d,
    uint4* __restrict__ H2a, _Float16* __restrict__ H2b,
    float* __restrict__ al2s8, float* __restrict__ al2s9, float* __restrict__ al2d) {
    __shared__ int2 lsr[4][64];
    const int lane = threadIdx.x & 63;
    const int wid = threadIdx.x >> 6;
    const int i = blockIdx.x * 4 + wid;
    const int p0 = RFL(off[i]);
    const int p1 = RFL(off[i + 1]);
    const float adv = al1d[i];
    float num[9], den[9];
#pragma unroll
    for (int k = 0; k < 9; ++k) { num[k] = 0.f; den[k] = 0.f; }

    for (int base = p0; base < p1; base += 64) {
        int m = p1 - base; if (m > 64) m = 64;
        // phase A: one edge per lane
        int sv = 0; float rv = 0.f;
        if (lane < m) {
            sv = csrc[base + lane];
            float z = al1s[sv] + adv;
            float c = z > 0.f ? z : NEG * z;       // leaky_relu (step-invariant)
            rv = __expf(c * (1.f / 9.f));          // w_k = rv^k
        }
        {
            float w = rv;
#pragma unroll
            for (int k = 0; k < 9; ++k) { den[k] += w; w *= rv; }  // per-lane partials
        }
        lsr[wid][lane] = make_int2(sv, __float_as_int(rv));
        asm volatile("s_waitcnt lgkmcnt(0)" ::: "memory");
        // phase B: 4 edges per iteration, 4 gathers in flight
        int j = 0;
        for (; j + 3 < m; j += 4) {
            int2 e0 = lsr[wid][j], e1 = lsr[wid][j + 1];
            int2 e2 = lsr[wid][j + 2], e3 = lsr[wid][j + 3];
            float h0 = H1[(size_t)e0.x * DD + lane];
            float h1v = H1[(size_t)e1.x * DD + lane];
            float h2v = H1[(size_t)e2.x * DD + lane];
            float h3v = H1[(size_t)e3.x * DD + lane];
            float r0 = __int_as_float(e0.y), r1 = __int_as_float(e1.y);
            float r2 = __int_as_float(e2.y), r3 = __int_as_float(e3.y);
            float w0 = r0, w1 = r1, w2 = r2, w3 = r3;
#pragma unroll
            for (int k = 0; k < 9; ++k) {
                num[k] = fmaf(w0, h0, num[k]);  w0 *= r0;
                num[k] = fmaf(w1, h1v, num[k]); w1 *= r1;
                num[k] = fmaf(w2, h2v, num[k]); w2 *= r2;
                num[k] = fmaf(w3, h3v, num[k]); w3 *= r3;
            }
        }
        for (; j < m; ++j) {
            int2 e0 = lsr[wid][j];
            float h0 = H1[(size_t)e0.x * DD + lane];
            float r0 = __int_as_float(e0.y);
            float w0 = r0;
#pragma unroll
            for (int k = 0; k < 9; ++k) { num[k] = fmaf(w0, h0, num[k]); w0 *= r0; }
        }
    }
    // reduce den partials across lanes
#pragma unroll
    for (int k = 0; k < 9; ++k) {
#pragma unroll
        for (int o = 32; o; o >>= 1) den[k] += __shfl_xor(den[k], o);
    }

    const float tss = t2s[lane];
    const float tdd = t2d[lane];
    float hm[9];
#pragma unroll
    for (int k = 0; k < 9; ++k) {
        float t = (float)(k + 1) * (1.f / 9.f);
        float v = (den[k] > 0.f) ? (t * num[k] / den[k]) : 0.f;
        hm[k] = (v > 0.f) ? v : expm1f(v);         // ELU
    }
#pragma unroll
    for (int k = 0; k < 9; ++k) {
        float ps = hm[k] * tss, pd = hm[k] * tdd;
#pragma unroll
        for (int o = 32; o; o >>= 1) { ps += __shfl_xor(ps, o); pd += __shfl_xor(pd, o); }
        if (lane == 0) {
            if (k < 8) al2s8[(size_t)i * 8 + k] = ps;
            else       al2s9[i] = ps;
            al2d[(size_t)i * 9 + k] = pd;
        }
    }
    union { _Float16 h[8]; uint4 u; } pk;
#pragma unroll
    for (int k = 0; k < 8; ++k) pk.h[k] = (_Float16)hm[k];
    H2a[(size_t)i * DD + lane] = pk.u;
    H2b[(size_t)i * DD + lane] = (_Float16)hm[8];
}

// ---- layer2: phase A (parallel 9 exps+den) -> LDS -> phase B (2-edge batches) ----
__global__ __launch_bounds__(256) void k_l2(
    const int* __restrict__ off, const int* __restrict__ csrc,
    const float* __restrict__ al2s8, const float* __restrict__ al2s9,
    const float* __restrict__ al2d,
    const uint4* __restrict__ H2a, const _Float16* __restrict__ H2b,
    const float* __restrict__ W2, float* __restrict__ out) {
    __shared__ float lw[4][64][12];   // [0..8]=w_k, [9]=src bits
    const int lane = threadIdx.x & 63;
    const int wid = threadIdx.x >> 6;
    const int i = blockIdx.x * 4 + wid;
    const int p0 = RFL(off[i]);
    const int p1 = RFL(off[i + 1]);
    float adv[9];
#pragma unroll
    for (int k = 0; k < 9; ++k) adv[k] = al2d[(size_t)i * 9 + k];
    float num[9], den[9];
#pragma unroll
    for (int k = 0; k < 9; ++k) { num[k] = 0.f; den[k] = 0.f; }

    for (int base = p0; base < p1; base += 64) {
        int m = p1 - base; if (m > 64) m = 64;
        // phase A: one edge per lane — parallel alpha gathers + 9 exps
        int sv = 0; float wv[9];
#pragma unroll
        for (int k = 0; k < 9; ++k) wv[k] = 0.f;
        if (lane < m) {
            sv = csrc[base + lane];
            const float4* pa = (const float4*)(al2s8 + (size_t)sv * 8);
            float4 A0 = pa[0], A1 = pa[1];
            float as[9] = {A0.x, A0.y, A0.z, A0.w, A1.x, A1.y, A1.z, A1.w, al2s9[sv]};
#pragma unroll
            for (int k = 0; k < 9; ++k) {
                float z = as[k] + adv[k];
                float lr = z > 0.f ? z : NEG * z;
                wv[k] = __expf(lr);
            }
        }
#pragma unroll
        for (int k = 0; k < 9; ++k) den[k] += wv[k];   // per-lane partials
        float* dst = &lw[wid][lane][0];
        *(float4*)dst       = make_float4(wv[0], wv[1], wv[2], wv[3]);
        *(float4*)(dst + 4) = make_float4(wv[4], wv[5], wv[6], wv[7]);
        dst[8] = wv[8];
        dst[9] = __int_as_float(sv);
        asm volatile("s_waitcnt lgkmcnt(0)" ::: "memory");
        // phase B: 2-edge batches — 4 global loads in flight before consumption
        int j = 0;
        for (; j + 1 < m; j += 2) {
            const float* s0 = &lw[wid][j][0];
            const float* s1 = &lw[wid][j + 1][0];
            int sj0 = __float_as_int(s0[9]);
            int sj1 = __float_as_int(s1[9]);
            union { uint4 v; _Float16 h[8]; } c0, c1;
            c0.v = H2a[(size_t)sj0 * DD + lane];
            c1.v = H2a[(size_t)sj1 * DD + lane];
            float h90 = (float)H2b[(size_t)sj0 * DD + lane];
            float h91 = (float)H2b[(size_t)sj1 * DD + lane];
            float4 wA0 = *(const float4*)s0, wB0 = *(const float4*)(s0 + 4);
            float4 wA1 = *(const float4*)s1, wB1 = *(const float4*)(s1 + 4);
            num[0] = fmaf(wA0.x, (float)c0.h[0], num[0]);
            num[1] = fmaf(wA0.y, (float)c0.h[1], num[1]);
            num[2] = fmaf(wA0.z, (float)c0.h[2], num[2]);
            num[3] = fmaf(wA0.w, (float)c0.h[3], num[3]);
            num[4] = fmaf(wB0.x, (float)c0.h[4], num[4]);
            num[5] = fmaf(wB0.y, (float)c0.h[5], num[5]);
            num[6] = fmaf(wB0.z, (float)c0.h[6], num[6]);
            num[7] = fmaf(wB0.w, (float)c0.h[7], num[7]);
            num[8] = fmaf(s0[8], h90, num[8]);
            num[0] = fmaf(wA1.x, (float)c1.h[0], num[0]);
            num[1] = fmaf(wA1.y, (float)c1.h[1], num[1]);
            num[2] = fmaf(wA1.z, (float)c1.h[2], num[2]);
            num[3] = fmaf(wA1.w, (float)c1.h[3], num[3]);
            num[4] = fmaf(wB1.x, (float)c1.h[4], num[4]);
            num[5] = fmaf(wB1.y, (float)c1.h[5], num[5]);
            num[6] = fmaf(wB1.z, (float)c1.h[6], num[6]);
            num[7] = fmaf(wB1.w, (float)c1.h[7], num[7]);
            num[8] = fmaf(s1[8], h91, num[8]);
        }
        if (j < m) {
            const float* s0 = &lw[wid][j][0];
            int sj0 = __float_as_int(s0[9]);
            union { uint4 v; _Float16 h[8]; } c0;
            c0.v = H2a[(size_t)sj0 * DD + lane];
            float h90 = (float)H2b[(size_t)sj0 * DD + lane];
            float4 wA0 = *(const float4*)s0, wB0 = *(const float4*)(s0 + 4);
            num[0] = fmaf(wA0.x, (float)c0.h[0], num[0]);
            num[1] = fmaf(wA0.y, (float)c0.h[1], num[1]);
            num[2] = fmaf(wA0.z, (float)c0.h[2], num[2]);
            num[3] = fmaf(wA0.w, (float)c0.h[3], num[3]);
            num[4] = fmaf(wB0.x, (float)c0.h[4], num[4]);
            num[5] = fmaf(wB0.y, (float)c0.h[5], num[5]);
            num[6] = fmaf(wB0.z, (float)c0.h[6], num[6]);
            num[7] = fmaf(wB0.w, (float)c0.h[7], num[7]);
            num[8] = fmaf(s0[8], h90, num[8]);
        }
    }
    // reduce den partials across lanes
#pragma unroll
    for (int k = 0; k < 9; ++k) {
#pragma unroll
        for (int o = 32; o; o >>= 1) den[k] += __shfl_xor(den[k], o);
    }
    // vsum[lane] = sum_k num/den, then one W2 matvec per node
    float vsum = 0.f;
#pragma unroll
    for (int k = 0; k < 9; ++k) vsum += (den[k] > 0.f) ? (num[k] / den[k]) : 0.f;
    float h2 = 0.f;
#pragma unroll 8
    for (int j = 0; j < DD; ++j) h2 = fmaf(__shfl(vsum, j), W2[j * DD + lane], h2);
    out[(size_t)i * DD + lane] = h2 * (1.f / 9.f);
}

extern "C" void kernel_launch(void* const* d_in, const int* in_sizes, int n_in,
                              void* d_out, int out_size, void* d_ws, size_t ws_size,
                              hipStream_t stream) {
    const float* x   = (const float*)d_in[0];
    const int*   ei1 = (const int*)d_in[1];
    const int*   ei2 = (const int*)d_in[2];
    const float* W1  = (const float*)d_in[3];
    const float* a1s = (const float*)d_in[4];
    const float* a1d = (const float*)d_in[5];
    const float* W2  = (const float*)d_in[6];
    const float* a2s = (const float*)d_in[7];
    const float* a2d = (const float*)d_in[8];
    float* out = (float*)d_out;

    const int* src1 = ei1;
    const int* dst1 = ei1 + NE;
    const int* src2 = ei2;
    const int* dst2 = ei2 + NE;

    // ---- workspace layout (4-byte words), ~81.6 MB total ----
    uint4* H2a   = (uint4*)d_ws;                          // NN*64 uint4 (51.2 MB)
    float* H1    = (float*)d_ws + (size_t)NN * 256;       // NN*DD
    float* al1s  = H1 + (size_t)NN * DD;                  // NN
    float* al1d  = al1s + NN;                             // NN
    float* al2s8 = al1d + NN;                             // NN*8
    float* al2s9 = al2s8 + (size_t)NN * 8;                // NN
    float* al2d  = al2s9 + NN;                            // NN*9
    _Float16* H2b = (_Float16*)(al2d + (size_t)NN * 9);   // NN*DD halves
    int* off1 = (int*)((float*)H2b + (size_t)NN * DD / 2);// NN+1
    int* off2 = off1 + (NN + 1);                          // NN+1
    int* cnt1 = off2 + (NN + 1);                          // NN
    int* cnt2 = cnt1 + NN;                                // NN (contiguous with cnt1)
    int* csr1 = cnt2 + NN;                                // NE
    int* csr2 = csr1 + NE;                                // NE
    float* t2s = (float*)(csr2 + NE);                     // 64
    float* t2d = t2s + DD;                                // 64

    const int EB = 256;
    const int EG4 = (NE / 4 + EB - 1) / EB;
    const int NB = NN / 4;  // wave per node

    hipMemsetAsync(cnt1, 0, 2 * NN * sizeof(int), stream);
    k_hist<<<EG4, EB, 0, stream>>>(dst1, dst2, cnt1, cnt2);
    k_scan<<<2, 1024, 0, stream>>>(cnt1, off1, cnt2, off2);
    hipMemsetAsync(cnt1, 0, 2 * NN * sizeof(int), stream);
    k_scatter<<<EG4, EB, 0, stream>>>(src1, dst1, off1, cnt1, csr1,
                                      src2, dst2, off2, cnt2, csr2);
    k_h1<<<NB, 256, 0, stream>>>(x, W1, a1s, a1d, H1, al1s, al1d);
    k_a2t<<<1, 64, 0, stream>>>(W2, a2s, a2d, t2s, t2d);

    k_l1<<<NB, 256, 0, stream>>>(off1, csr1, al1s, al1d, H1,
                                 t2s, t2d, H2a, H2b, al2s8, al2s9, al2d);
    k_l2<<<NB, 256, 0, stream>>>(off2, csr2, al2s8, al2s9, al2d, H2a, H2b, W2, out);
}

// Round 13
// 473.921 us; speedup vs baseline: 1.2004x; 1.1785x over previous
//
#include <hip/hip_runtime.h>
#include <hip/hip_bf16.h>

#define NN 50000
#define NE 800000
#define DD 64
#define NEG 0.2f

#define RFL(x) __builtin_amdgcn_readfirstlane(x)
typedef unsigned short u16;

// ---------------- CSR build: hist + rank (one atomic pass) ----------------
__global__ void k_hist(const int* __restrict__ dst1, const int* __restrict__ dst2,
                       int* __restrict__ cnt1, int* __restrict__ cnt2,
                       int* __restrict__ rank1, int* __restrict__ rank2) {
    int t = blockIdx.x * blockDim.x + threadIdx.x;
    if (t < NE / 4) {
        int4 d1 = ((const int4*)dst1)[t];
        int4 d2 = ((const int4*)dst2)[t];
        int4 r1, r2;
        r1.x = atomicAdd(&cnt1[d1.x], 1); r1.y = atomicAdd(&cnt1[d1.y], 1);
        r1.z = atomicAdd(&cnt1[d1.z], 1); r1.w = atomicAdd(&cnt1[d1.w], 1);
        r2.x = atomicAdd(&cnt2[d2.x], 1); r2.y = atomicAdd(&cnt2[d2.y], 1);
        r2.z = atomicAdd(&cnt2[d2.z], 1); r2.w = atomicAdd(&cnt2[d2.w], 1);
        ((int4*)rank1)[t] = r1;
        ((int4*)rank2)[t] = r2;
    }
}

__global__ __launch_bounds__(1024) void k_scan(const int* __restrict__ cnt1, int* __restrict__ off1,
                                               const int* __restrict__ cnt2, int* __restrict__ off2) {
    const int* cnt = blockIdx.x ? cnt2 : cnt1;
    int* off = blockIdx.x ? off2 : off1;
    __shared__ int lds[1024];
    const int tid = threadIdx.x;
    const int CH = (NN + 1023) / 1024;  // 49
    const int base = tid * CH;
    int s = 0;
    for (int q = 0; q < CH; ++q) {
        int idx = base + q;
        if (idx < NN) s += cnt[idx];
    }
    lds[tid] = s;
    __syncthreads();
    for (int d = 1; d < 1024; d <<= 1) {
        int v = (tid >= d) ? lds[tid - d] : 0;
        __syncthreads();
        lds[tid] += v;
        __syncthreads();
    }
    int run = tid ? lds[tid - 1] : 0;
    for (int q = 0; q < CH; ++q) {
        int idx = base + q;
        if (idx < NN) { off[idx] = run; run += cnt[idx]; }
    }
    if (tid == 1023) off[NN] = lds[1023];
}

// ---------------- placement: no atomics, independent 2B stores ----------------
__global__ void k_place(const int* __restrict__ src1, const int* __restrict__ dst1,
                        const int* __restrict__ off1, const int* __restrict__ rank1,
                        u16* __restrict__ csr1,
                        const int* __restrict__ src2, const int* __restrict__ dst2,
                        const int* __restrict__ off2, const int* __restrict__ rank2,
                        u16* __restrict__ csr2) {
    int t = blockIdx.x * blockDim.x + threadIdx.x;
    if (t < NE / 4) {
        int4 s1 = ((const int4*)src1)[t];
        int4 d1 = ((const int4*)dst1)[t];
        int4 r1 = ((const int4*)rank1)[t];
        int4 s2 = ((const int4*)src2)[t];
        int4 d2 = ((const int4*)dst2)[t];
        int4 r2 = ((const int4*)rank2)[t];
        csr1[off1[d1.x] + r1.x] = (u16)s1.x;
        csr1[off1[d1.y] + r1.y] = (u16)s1.y;
        csr1[off1[d1.z] + r1.z] = (u16)s1.z;
        csr1[off1[d1.w] + r1.w] = (u16)s1.w;
        csr2[off2[d2.x] + r2.x] = (u16)s2.x;
        csr2[off2[d2.y] + r2.y] = (u16)s2.y;
        csr2[off2[d2.z] + r2.z] = (u16)s2.z;
        csr2[off2[d2.w] + r2.w] = (u16)s2.w;
    }
}

// ---------------- H1 = x @ W1 (stored fp16), alpha1 = H1 @ a1_{src,dst} ----------------
__global__ __launch_bounds__(256) void k_h1(
    const float* __restrict__ x, const float* __restrict__ W1,
    const float* __restrict__ a1s, const float* __restrict__ a1d,
    _Float16* __restrict__ H1h, float* __restrict__ al1s, float* __restrict__ al1d) {
    const int lane = threadIdx.x & 63;
    const int i = blockIdx.x * 4 + (threadIdx.x >> 6);
    const float xv = x[i * DD + lane];
    float h = 0.f;
#pragma unroll
    for (int j = 0; j < DD; ++j) h = fmaf(__shfl(xv, j), W1[j * DD + lane], h);
    H1h[(size_t)i * DD + lane] = (_Float16)h;
    float ps = h * a1s[lane], pd = h * a1d[lane];
#pragma unroll
    for (int o = 32; o; o >>= 1) { ps += __shfl_xor(ps, o); pd += __shfl_xor(pd, o); }
    if (lane == 0) { al1s[i] = ps; al1d[i] = pd; }
}

// ---------------- t2s = W2 @ a2s, t2d = W2 @ a2d ----------------
__global__ void k_a2t(const float* __restrict__ W2, const float* __restrict__ a2s,
                      const float* __restrict__ a2d, float* __restrict__ t2s,
                      float* __restrict__ t2d) {
    int j = threadIdx.x & 63;
    float ss = 0.f, sd = 0.f;
#pragma unroll
    for (int d = 0; d < DD; ++d) {
        float w = W2[j * DD + d];
        ss = fmaf(w, a2s[d], ss);
        sd = fmaf(w, a2d[d], sd);
    }
    t2s[j] = ss;
    t2d[j] = sd;
}

// ---- layer1: phase A (parallel score+den) -> LDS -> phase B (fp16 gathers, 4 in flight) ----
__global__ __launch_bounds__(256) void k_l1(
    const int* __restrict__ off, const u16* __restrict__ csrc,
    const float* __restrict__ al1s, const float* __restrict__ al1d,
    const _Float16* __restrict__ H1h,
    const float* __restrict__ t2s, const float* __restrict__ t2d,
    uint4* __restrict__ H2a, _Float16* __restrict__ H2b,
    float* __restrict__ al2s8, float* __restrict__ al2s9, float* __restrict__ al2d) {
    __shared__ int2 lsr[4][64];
    const int lane = threadIdx.x & 63;
    const int wid = threadIdx.x >> 6;
    const int i = blockIdx.x * 4 + wid;
    const int p0 = RFL(off[i]);
    const int p1 = RFL(off[i + 1]);
    const float adv = al1d[i];
    float num[9], den[9];
#pragma unroll
    for (int k = 0; k < 9; ++k) { num[k] = 0.f; den[k] = 0.f; }

    for (int base = p0; base < p1; base += 64) {
        int m = p1 - base; if (m > 64) m = 64;
        // phase A: one edge per lane
        int sv = 0; float rv = 0.f;
        if (lane < m) {
            sv = csrc[base + lane];
            float z = al1s[sv] + adv;
            float c = z > 0.f ? z : NEG * z;       // leaky_relu (step-invariant)
            rv = __expf(c * (1.f / 9.f));          // w_k = rv^k
        }
        {
            float w = rv;
#pragma unroll
            for (int k = 0; k < 9; ++k) { den[k] += w; w *= rv; }  // per-lane partials
        }
        lsr[wid][lane] = make_int2(sv, __float_as_int(rv));
        asm volatile("s_waitcnt lgkmcnt(0)" ::: "memory");
        // phase B: 4 edges per iteration, 4 fp16 gathers in flight
        int j = 0;
        for (; j + 3 < m; j += 4) {
            int2 e0 = lsr[wid][j], e1 = lsr[wid][j + 1];
            int2 e2 = lsr[wid][j + 2], e3 = lsr[wid][j + 3];
            float h0 = (float)H1h[(size_t)e0.x * DD + lane];
            float h1v = (float)H1h[(size_t)e1.x * DD + lane];
            float h2v = (float)H1h[(size_t)e2.x * DD + lane];
            float h3v = (float)H1h[(size_t)e3.x * DD + lane];
            float r0 = __int_as_float(e0.y), r1 = __int_as_float(e1.y);
            float r2 = __int_as_float(e2.y), r3 = __int_as_float(e3.y);
            float w0 = r0, w1 = r1, w2 = r2, w3 = r3;
#pragma unroll
            for (int k = 0; k < 9; ++k) {
                num[k] = fmaf(w0, h0, num[k]);  w0 *= r0;
                num[k] = fmaf(w1, h1v, num[k]); w1 *= r1;
                num[k] = fmaf(w2, h2v, num[k]); w2 *= r2;
                num[k] = fmaf(w3, h3v, num[k]); w3 *= r3;
            }
        }
        for (; j < m; ++j) {
            int2 e0 = lsr[wid][j];
            float h0 = (float)H1h[(size_t)e0.x * DD + lane];
            float r0 = __int_as_float(e0.y);
            float w0 = r0;
#pragma unroll
            for (int k = 0; k < 9; ++k) { num[k] = fmaf(w0, h0, num[k]); w0 *= r0; }
        }
    }
    // reduce den partials across lanes
#pragma unroll
    for (int k = 0; k < 9; ++k) {
#pragma unroll
        for (int o = 32; o; o >>= 1) den[k] += __shfl_xor(den[k], o);
    }

    const float tss = t2s[lane];
    const float tdd = t2d[lane];
    float hm[9];
#pragma unroll
    for (int k = 0; k < 9; ++k) {
        float t = (float)(k + 1) * (1.f / 9.f);
        float v = (den[k] > 0.f) ? (t * num[k] / den[k]) : 0.f;
        hm[k] = (v > 0.f) ? v : expm1f(v);         // ELU
    }
#pragma unroll
    for (int k = 0; k < 9; ++k) {
        float ps = hm[k] * tss, pd = hm[k] * tdd;
#pragma unroll
        for (int o = 32; o; o >>= 1) { ps += __shfl_xor(ps, o); pd += __shfl_xor(pd, o); }
        if (lane == 0) {
            if (k < 8) al2s8[(size_t)i * 8 + k] = ps;
            else       al2s9[i] = ps;
            al2d[(size_t)i * 9 + k] = pd;
        }
    }
    union { _Float16 h[8]; uint4 u; } pk;
#pragma unroll
    for (int k = 0; k < 8; ++k) pk.h[k] = (_Float16)hm[k];
    H2a[(size_t)i * DD + lane] = pk.u;
    H2b[(size_t)i * DD + lane] = (_Float16)hm[8];
}

// ---- layer2: phase A (parallel 9 exps+den) -> LDS -> phase B -> one W2 matvec ----
__global__ __launch_bounds__(256) void k_l2(
    const int* __restrict__ off, const u16* __restrict__ csrc,
    const float* __restrict__ al2s8, const float* __restrict__ al2s9,
    const float* __restrict__ al2d,
    const uint4* __restrict__ H2a, const _Float16* __restrict__ H2b,
    const float* __restrict__ W2, float* __restrict__ out) {
    __shared__ float lw[4][64][12];   // [0..8]=w_k, [9]=src bits
    const int lane = threadIdx.x & 63;
    const int wid = threadIdx.x >> 6;
    const int i = blockIdx.x * 4 + wid;
    const int p0 = RFL(off[i]);
    const int p1 = RFL(off[i + 1]);
    float adv[9];
#pragma unroll
    for (int k = 0; k < 9; ++k) adv[k] = al2d[(size_t)i * 9 + k];
    float num[9], den[9];
#pragma unroll
    for (int k = 0; k < 9; ++k) { num[k] = 0.f; den[k] = 0.f; }

    for (int base = p0; base < p1; base += 64) {
        int m = p1 - base; if (m > 64) m = 64;
        // phase A: one edge per lane — parallel alpha gathers + 9 exps
        int sv = 0; float wv[9];
#pragma unroll
        for (int k = 0; k < 9; ++k) wv[k] = 0.f;
        if (lane < m) {
            sv = csrc[base + lane];
            const float4* pa = (const float4*)(al2s8 + (size_t)sv * 8);
            float4 A0 = pa[0], A1 = pa[1];
            float as[9] = {A0.x, A0.y, A0.z, A0.w, A1.x, A1.y, A1.z, A1.w, al2s9[sv]};
#pragma unroll
            for (int k = 0; k < 9; ++k) {
                float z = as[k] + adv[k];
                float lr = z > 0.f ? z : NEG * z;
                wv[k] = __expf(lr);
            }
        }
#pragma unroll
        for (int k = 0; k < 9; ++k) den[k] += wv[k];   // per-lane partials
        float* dst = &lw[wid][lane][0];
        *(float4*)dst       = make_float4(wv[0], wv[1], wv[2], wv[3]);
        *(float4*)(dst + 4) = make_float4(wv[4], wv[5], wv[6], wv[7]);
        dst[8] = wv[8];
        dst[9] = __int_as_float(sv);
        asm volatile("s_waitcnt lgkmcnt(0)" ::: "memory");
        // phase B: 2-edge batches — 4 global loads in flight before consumption
        int j = 0;
        for (; j + 1 < m; j += 2) {
            const float* s0 = &lw[wid][j][0];
            const float* s1 = &lw[wid][j + 1][0];
            int sj0 = __float_as_int(s0[9]);
            int sj1 = __float_as_int(s1[9]);
            union { uint4 v; _Float16 h[8]; } c0, c1;
            c0.v = H2a[(size_t)sj0 * DD + lane];
            c1.v = H2a[(size_t)sj1 * DD + lane];
            float h90 = (float)H2b[(size_t)sj0 * DD + lane];
            float h91 = (float)H2b[(size_t)sj1 * DD + lane];
            float4 wA0 = *(const float4*)s0, wB0 = *(const float4*)(s0 + 4);
            float4 wA1 = *(const float4*)s1, wB1 = *(const float4*)(s1 + 4);
            num[0] = fmaf(wA0.x, (float)c0.h[0], num[0]);
            num[1] = fmaf(wA0.y, (float)c0.h[1], num[1]);
            num[2] = fmaf(wA0.z, (float)c0.h[2], num[2]);
            num[3] = fmaf(wA0.w, (float)c0.h[3], num[3]);
            num[4] = fmaf(wB0.x, (float)c0.h[4], num[4]);
            num[5] = fmaf(wB0.y, (float)c0.h[5], num[5]);
            num[6] = fmaf(wB0.z, (float)c0.h[6], num[6]);
            num[7] = fmaf(wB0.w, (float)c0.h[7], num[7]);
            num[8] = fmaf(s0[8], h90, num[8]);
            num[0] = fmaf(wA1.x, (float)c1.h[0], num[0]);
            num[1] = fmaf(wA1.y, (float)c1.h[1], num[1]);
            num[2] = fmaf(wA1.z, (float)c1.h[2], num[2]);
            num[3] = fmaf(wA1.w, (float)c1.h[3], num[3]);
            num[4] = fmaf(wB1.x, (float)c1.h[4], num[4]);
            num[5] = fmaf(wB1.y, (float)c1.h[5], num[5]);
            num[6] = fmaf(wB1.z, (float)c1.h[6], num[6]);
            num[7] = fmaf(wB1.w, (float)c1.h[7], num[7]);
            num[8] = fmaf(s1[8], h91, num[8]);
        }
        if (j < m) {
            const float* s0 = &lw[wid][j][0];
            int sj0 = __float_as_int(s0[9]);
            union { uint4 v; _Float16 h[8]; } c0;
            c0.v = H2a[(size_t)sj0 * DD + lane];
            float h90 = (float)H2b[(size_t)sj0 * DD + lane];
            float4 wA0 = *(const float4*)s0, wB0 = *(const float4*)(s0 + 4);
            num[0] = fmaf(wA0.x, (float)c0.h[0], num[0]);
            num[1] = fmaf(wA0.y, (float)c0.h[1], num[1]);
            num[2] = fmaf(wA0.z, (float)c0.h[2], num[2]);
            num[3] = fmaf(wA0.w, (float)c0.h[3], num[3]);
            num[4] = fmaf(wB0.x, (float)c0.h[4], num[4]);
            num[5] = fmaf(wB0.y, (float)c0.h[5], num[5]);
            num[6] = fmaf(wB0.z, (float)c0.h[6], num[6]);
            num[7] = fmaf(wB0.w, (float)c0.h[7], num[7]);
            num[8] = fmaf(s0[8], h90, num[8]);
        }
    }
    // reduce den partials across lanes
#pragma unroll
    for (int k = 0; k < 9; ++k) {
#pragma unroll
        for (int o = 32; o; o >>= 1) den[k] += __shfl_xor(den[k], o);
    }
    // vsum[lane] = sum_k num/den, then one W2 matvec per node
    float vsum = 0.f;
#pragma unroll
    for (int k = 0; k < 9; ++k) vsum += (den[k] > 0.f) ? (num[k] / den[k]) : 0.f;
    float h2 = 0.f;
#pragma unroll 8
    for (int j = 0; j < DD; ++j) h2 = fmaf(__shfl(vsum, j), W2[j * DD + lane], h2);
    out[(size_t)i * DD + lane] = h2 * (1.f / 9.f);
}

extern "C" void kernel_launch(void* const* d_in, const int* in_sizes, int n_in,
                              void* d_out, int out_size, void* d_ws, size_t ws_size,
                              hipStream_t stream) {
    const float* x   = (const float*)d_in[0];
    const int*   ei1 = (const int*)d_in[1];
    const int*   ei2 = (const int*)d_in[2];
    const float* W1  = (const float*)d_in[3];
    const float* a1s = (const float*)d_in[4];
    const float* a1d = (const float*)d_in[5];
    const float* W2  = (const float*)d_in[6];
    const float* a2s = (const float*)d_in[7];
    const float* a2d = (const float*)d_in[8];
    float* out = (float*)d_out;

    const int* src1 = ei1;
    const int* dst1 = ei1 + NE;
    const int* src2 = ei2;
    const int* dst2 = ei2 + NE;

    // ---- workspace layout (4-byte words), ~78.4 MB total ----
    uint4* H2a    = (uint4*)d_ws;                           // NN*64 uint4 (12.8M words)
    _Float16* H1h = (_Float16*)((float*)d_ws + (size_t)NN * 256); // NN*DD halves (1.6M words)
    float* al1s   = (float*)H1h + (size_t)NN * DD / 2;      // NN
    float* al1d   = al1s + NN;                              // NN
    float* al2s8  = al1d + NN;                              // NN*8 (16B-aligned: offset%4==0)
    float* al2s9  = al2s8 + (size_t)NN * 8;                 // NN
    float* al2d   = al2s9 + NN;                             // NN*9
    _Float16* H2b = (_Float16*)(al2d + (size_t)NN * 9);     // NN*DD halves (1.6M words)
    int* rank1 = (int*)((float*)H2b + (size_t)NN * DD / 2); // NE (16B-aligned)
    int* rank2 = rank1 + NE;                                // NE
    u16* csr1  = (u16*)(rank2 + NE);                        // NE ushorts
    u16* csr2  = csr1 + NE;                                 // NE ushorts
    float* t2s = (float*)(csr2 + NE);                       // 64
    float* t2d = t2s + DD;                                  // 64
    int* off1 = (int*)(t2d + DD);                           // NN+1
    int* off2 = off1 + (NN + 1);                            // NN+1
    int* cnt1 = off2 + (NN + 1);                            // NN
    int* cnt2 = cnt1 + NN;                                  // NN (contiguous with cnt1)

    const int EB = 256;
    const int EG4 = (NE / 4 + EB - 1) / EB;
    const int NB = NN / 4;  // wave per node

    hipMemsetAsync(cnt1, 0, 2 * NN * sizeof(int), stream);
    k_hist<<<EG4, EB, 0, stream>>>(dst1, dst2, cnt1, cnt2, rank1, rank2);
    k_scan<<<2, 1024, 0, stream>>>(cnt1, off1, cnt2, off2);
    k_place<<<EG4, EB, 0, stream>>>(src1, dst1, off1, rank1, csr1,
                                    src2, dst2, off2, rank2, csr2);
    k_h1<<<NB, 256, 0, stream>>>(x, W1, a1s, a1d, H1h, al1s, al1d);
    k_a2t<<<1, 64, 0, stream>>>(W2, a2s, a2d, t2s, t2d);

    k_l1<<<NB, 256, 0, stream>>>(off1, csr1, al1s, al1d, H1h,
                                 t2s, t2d, H2a, H2b, al2s8, al2s9, al2d);
    k_l2<<<NB, 256, 0, stream>>>(off2, csr2, al2s8, al2s9, al2d, H2a, H2b, W2, out);
}